// Round 8
// baseline (587.390 us; speedup 1.0000x reference)
//
#include <hip/hip_runtime.h>
#include <hip/hip_bf16.h>

typedef __attribute__((ext_vector_type(8))) short bf16x8;
typedef __attribute__((ext_vector_type(4))) short short4v;
typedef __attribute__((ext_vector_type(4))) float floatx4;

#define MFMA16(A, B, C) __builtin_amdgcn_mfma_f32_16x16x32_bf16((A), (B), (C), 0, 0, 0)

__device__ inline short bf16bits(float f) {
  __hip_bfloat16 h = __float2bfloat16(f);
  return *reinterpret_cast<short*>(&h);
}
__device__ inline unsigned pk(float lo, float hi) {
  return (unsigned)(unsigned short)bf16bits(lo) |
         ((unsigned)(unsigned short)bf16bits(hi) << 16);
}
typedef __attribute__((address_space(3))) char lds_char;
typedef __attribute__((address_space(1))) const char glob_char;
__device__ inline void gll16(const void* g, void* l) {
  __builtin_amdgcn_global_load_lds((glob_char*)g, (lds_char*)l, 16, 0, 0);
}

// ---------------------------------------------------------------------------
// 64x64-tiled transpose, fp32 source -> bf16 dest: dst[c][r] = bf16(src[r*ldS+c])
// ---------------------------------------------------------------------------
__global__ __launch_bounds__(256) void transpose_f2b_kernel(
    const float* __restrict__ src, __hip_bfloat16* __restrict__ dst,
    int R, int C, int ldS) {
  __shared__ __align__(16) __hip_bfloat16 tile[64][72];
  const long r0 = (long)blockIdx.y * 64, c0 = (long)blockIdx.x * 64;
  for (int i = threadIdx.x; i < 1024; i += 256) {
    int r = i >> 4, c4 = (i & 15) * 4;
    float4 f = *(const float4*)&src[(r0 + r) * ldS + c0 + c4];
    short4v s;
    s[0] = bf16bits(f.x); s[1] = bf16bits(f.y);
    s[2] = bf16bits(f.z); s[3] = bf16bits(f.w);
    *(short4v*)&tile[r][c4] = s;
  }
  __syncthreads();
  for (int i = threadIdx.x; i < 512; i += 256) {
    int c = i >> 3, r8 = (i & 7) * 8;
    bf16x8 sv;
#pragma unroll
    for (int j = 0; j < 8; j++) sv[j] = *reinterpret_cast<const short*>(&tile[r8 + j][c]);
    *(bf16x8*)&dst[(c0 + c) * R + r0 + r8] = sv;
  }
}

// ---------------------------------------------------------------------------
// V transpose: qkv[B*S][3072] (bf16, V at col 2048 + h*64) -> vt[B*H][64][2048]
// ---------------------------------------------------------------------------
__global__ __launch_bounds__(256) void vtrans_kernel(
    const __hip_bfloat16* __restrict__ qkv, __hip_bfloat16* __restrict__ vt) {
  __shared__ __align__(16) __hip_bfloat16 tile[64][72];
  const int bh = blockIdx.y, b = bh >> 4, h = bh & 15;
  const long s0 = (long)blockIdx.x * 64;
  const __hip_bfloat16* src = qkv + ((long)b * 2048 + s0) * 3072 + 2048 + h * 64;
  for (int i = threadIdx.x; i < 512; i += 256) {
    int s = i >> 3, d8 = (i & 7) * 8;
    *(uint4*)&tile[s][d8] = *(const uint4*)&src[(long)s * 3072 + d8];
  }
  __syncthreads();
  __hip_bfloat16* dstb = vt + (long)bh * 64 * 2048 + s0;
  for (int i = threadIdx.x; i < 512; i += 256) {
    int d = i >> 3, s8 = (i & 7) * 8;
    bf16x8 sv;
#pragma unroll
    for (int j = 0; j < 8; j++) sv[j] = *reinterpret_cast<const short*>(&tile[s8 + j][d]);
    *(bf16x8*)&dstb[(long)d * 2048 + s8] = sv;
  }
}

// ---------------------------------------------------------------------------
// mask -> additive bias: 0 if mask!=0 else -1e30
// ---------------------------------------------------------------------------
__global__ __launch_bounds__(256) void mask2add_kernel(
    const int* __restrict__ mask, float* __restrict__ addm) {
  int i = blockIdx.x * 256 + threadIdx.x;
  addm[i] = mask[i] ? 0.f : -1e30f;
}

// ---------------------------------------------------------------------------
// d_out = x1 + b2 (broadcast over rows), fp32
// ---------------------------------------------------------------------------
__global__ __launch_bounds__(256) void bias_add_kernel(
    const float* __restrict__ x1, const float* __restrict__ b2,
    float* __restrict__ out) {
  const int i = (blockIdx.x * 256 + threadIdx.x) * 4;
  float4 v = *(const float4*)&x1[i];
  const float4 bb = *(const float4*)&b2[i & 1023];
  v.x += bb.x; v.y += bb.y; v.z += bb.z; v.w += bb.w;
  *(float4*)&out[i] = v;
}

// ---------------------------------------------------------------------------
// LayerNorm: 1 block per 1024-elem row. ddof=1, eps added to std. fp32 -> bf16.
// ---------------------------------------------------------------------------
__global__ __launch_bounds__(256) void ln_kernel(
    const float* __restrict__ x, __hip_bfloat16* __restrict__ y,
    const float* __restrict__ alpha_p, const float* __restrict__ bias_p) {
  __shared__ float sred[8];
  const long row = blockIdx.x;
  const int t = threadIdx.x;
  const float* xr = x + row * 1024;
  float v[4];
#pragma unroll
  for (int i = 0; i < 4; i++) v[i] = xr[t * 4 + i];
  float sum = 0.f, sq = 0.f;
#pragma unroll
  for (int i = 0; i < 4; i++) { sum += v[i]; sq += v[i] * v[i]; }
#pragma unroll
  for (int off = 32; off; off >>= 1) {
    sum += __shfl_down(sum, off);
    sq += __shfl_down(sq, off);
  }
  if ((t & 63) == 0) { sred[(t >> 6) * 2] = sum; sred[(t >> 6) * 2 + 1] = sq; }
  __syncthreads();
  sum = sred[0] + sred[2] + sred[4] + sred[6];
  sq = sred[1] + sred[3] + sred[5] + sred[7];
  const float mean = sum * (1.f / 1024.f);
  float var = (sq - 1024.f * mean * mean) * (1.f / 1023.f);
  var = fmaxf(var, 0.f);
  const float denom = sqrtf(var) + 1e-5f;
  const float sc = alpha_p[0] / denom;
  const float beta = bias_p[0];
  __hip_bfloat16* yr = y + row * 1024;
#pragma unroll
  for (int i = 0; i < 4; i++) yr[t * 4 + i] = __float2bfloat16((v[i] - mean) * sc + beta);
}

// ---------------------------------------------------------------------------
// bf16 GEMM, B pre-transposed: C[M][N] = A[M][K] @ Bt[N][K]^T
// m97-style staging: global_load_lds width=16.
// EPI: 0 = bf16 store; 1 = (+f32 res)->f32; 2 = (+bias, relu)->bf16;
//      3 = f32 C += v
// ---------------------------------------------------------------------------
template <int EPI>
__global__ __launch_bounds__(256) void gemm_bt_kernel(
    const __hip_bfloat16* __restrict__ A, const __hip_bfloat16* __restrict__ Bt,
    void* __restrict__ Cv, const float* __restrict__ bias,
    const float* __restrict__ res, int M, int N, int K) {
  __shared__ __align__(16) __hip_bfloat16 lA[128 * 32];
  __shared__ __align__(16) __hip_bfloat16 lB[128 * 32];
  const int tid = threadIdx.x;
  const int wave = tid >> 6, lane = tid & 63;
  const int quad = lane >> 4, l16 = lane & 15;
  const int wm = wave >> 1, wn = wave & 1;
  const long m0 = (long)blockIdx.y * 128;
  const long n0 = (long)blockIdx.x * 128;

  const int rA0 = tid >> 2, cA0 = (tid & 3) * 8;
  const int rA1 = (tid + 256) >> 2, cA1 = ((tid + 256) & 3) * 8;

  floatx4 acc[4][4];
#pragma unroll
  for (int i = 0; i < 4; i++)
#pragma unroll
    for (int j = 0; j < 4; j++) acc[i][j] = (floatx4){0.f, 0.f, 0.f, 0.f};

  const __hip_bfloat16* Ab = A + m0 * K;
  const __hip_bfloat16* Bb = Bt + n0 * K;

  for (int k0 = 0; k0 < K; k0 += 32) {
    __syncthreads();
    gll16(&Ab[(long)rA0 * K + k0 + cA0], &lA[wave * 512]);
    gll16(&Ab[(long)rA1 * K + k0 + cA1], &lA[2048 + wave * 512]);
    gll16(&Bb[(long)rA0 * K + k0 + cA0], &lB[wave * 512]);
    gll16(&Bb[(long)rA1 * K + k0 + cA1], &lB[2048 + wave * 512]);
    __syncthreads();
    bf16x8 af[4], bfr[4];
#pragma unroll
    for (int mi = 0; mi < 4; mi++)
      af[mi] = *(const bf16x8*)&lA[(wm * 64 + mi * 16 + l16) * 32 + quad * 8];
#pragma unroll
    for (int ni = 0; ni < 4; ni++)
      bfr[ni] = *(const bf16x8*)&lB[(wn * 64 + ni * 16 + l16) * 32 + quad * 8];
#pragma unroll
    for (int mi = 0; mi < 4; mi++)
#pragma unroll
      for (int ni = 0; ni < 4; ni++)
        acc[mi][ni] = MFMA16(af[mi], bfr[ni], acc[mi][ni]);
  }

#pragma unroll
  for (int mi = 0; mi < 4; mi++) {
#pragma unroll
    for (int ni = 0; ni < 4; ni++) {
#pragma unroll
      for (int r = 0; r < 4; r++) {
        const long row = m0 + wm * 64 + mi * 16 + quad * 4 + r;
        const long col = n0 + wn * 64 + ni * 16 + l16;
        const long idx = row * N + col;
        float v = acc[mi][ni][r];
        if (EPI == 0) {
          ((__hip_bfloat16*)Cv)[idx] = __float2bfloat16(v);
        } else if (EPI == 1) {
          ((float*)Cv)[idx] = v + res[idx];
        } else if (EPI == 2) {
          v += bias[col];
          ((__hip_bfloat16*)Cv)[idx] = __float2bfloat16(fmaxf(v, 0.f));
        } else if (EPI == 3) {
          float* Cf = (float*)Cv;
          Cf[idx] = Cf[idx] + v;
        }
      }
    }
  }
}

// ---------------------------------------------------------------------------
// Flash attention v5: identical pipeline to v4 (register-prefetch staging,
// two-barrier LDS tile, XOR swizzle, register-shfl P^T) but with
// __launch_bounds__(256, 4): grid is 4 blocks/CU anyway, so cap VGPRs at 128
// instead of 64 — round 7's 64-VGPR cap spilled the prefetch regs to scratch
// (WRITE_SIZE 8 MB -> 299 MB, attn 115 -> 185 us).
// ---------------------------------------------------------------------------
__global__ __launch_bounds__(256, 4) void attn_kernel(
    const __hip_bfloat16* __restrict__ qkv, const __hip_bfloat16* __restrict__ vt,
    const float* __restrict__ addm, __hip_bfloat16* __restrict__ ctx) {
  __shared__ __align__(16) __hip_bfloat16 lK[64 * 64];
  __shared__ __align__(16) __hip_bfloat16 lV[64 * 64];
  const int tid = threadIdx.x, wave = tid >> 6, lane = tid & 63;
  const int quad = lane >> 4, l16 = lane & 15;
  const int bh = blockIdx.y, b = bh >> 4, h = bh & 15;
  const int q0 = blockIdx.x * 64 + wave * 16;
  const float cs = 0.18033688011112042f;  // log2(e)/sqrt(64)

  const __hip_bfloat16* kb = qkv + (long)b * 2048 * 3072 + 1024 + h * 64;
  const __hip_bfloat16* vb = vt + (long)bh * 64 * 2048;
  const float* am = addm + b * 2048;

  // Q B-frags: Q[q=l16][kd=quad*8+j]
  const long qoff = ((long)b * 2048 + q0 + l16) * 3072 + h * 64;
  const bf16x8 bq0 = *(const bf16x8*)&qkv[qoff + quad * 8];
  const bf16x8 bq1 = *(const bf16x8*)&qkv[qoff + 32 + quad * 8];

  // staging: lane -> (row = wave*16 + j*8 + lane/8, slot = lane&7),
  // global chunk cg = slot ^ (row&7) stored at LDS[row][slot]
  const int srow = lane >> 3;
  const int cslot = lane & 7;
  const int cg = cslot ^ srow;
  const int wrow0 = wave * 16 + srow;  // j=0 row; j=1 adds 8

  floatx4 o[4];
#pragma unroll
  for (int mi = 0; mi < 4; mi++) o[mi] = (floatx4){0.f, 0.f, 0.f, 0.f};
  float mrow = -3.0e38f, lrow = 0.f;

  uint4 rK[2], rV[2];
#pragma unroll
  for (int j = 0; j < 2; ++j) {
    rK[j] = *(const uint4*)&kb[(long)(wrow0 + j * 8) * 3072 + cg * 8];
    rV[j] = *(const uint4*)&vb[(long)(wrow0 + j * 8) * 2048 + cg * 8];
  }

  for (int t = 0; t < 32; ++t) {
    __syncthreads();  // WAR: all waves done reading previous tile
#pragma unroll
    for (int j = 0; j < 2; ++j) {
      *(uint4*)&lK[(wrow0 + j * 8) * 64 + cslot * 8] = rK[j];
      *(uint4*)&lV[(wrow0 + j * 8) * 64 + cslot * 8] = rV[j];
    }
    __syncthreads();  // RAW: LDS tile visible
    if (t + 1 < 32) {
#pragma unroll
      for (int j = 0; j < 2; ++j) {
        rK[j] = *(const uint4*)&kb[(long)((t + 1) * 64 + wrow0 + j * 8) * 3072 + cg * 8];
        rV[j] = *(const uint4*)&vb[(long)(wrow0 + j * 8) * 2048 + (t + 1) * 64 + cg * 8];
      }
    }

    // S^T: 4 groups of 16 kv rows
    floatx4 c[4];
#pragma unroll
    for (int g = 0; g < 4; ++g) {
      const bf16x8 a0 =
          *(const bf16x8*)&lK[(g * 16 + l16) * 64 + ((quad) ^ (l16 & 7)) * 8];
      const bf16x8 a1 =
          *(const bf16x8*)&lK[(g * 16 + l16) * 64 + ((4 + quad) ^ (l16 & 7)) * 8];
      floatx4 cc = {0.f, 0.f, 0.f, 0.f};
      cc = MFMA16(a0, bq0, cc);
      cc = MFMA16(a1, bq1, cc);
      c[g] = cc;
    }
    // scores (log2 domain) + additive mask
    float s[4][4];
    float tm = -3.0e38f;
#pragma unroll
    for (int g = 0; g < 4; ++g) {
      const float4 a4 = *(const float4*)&am[t * 64 + g * 16 + quad * 4];
#pragma unroll
      for (int r = 0; r < 4; ++r) {
        const float av = r == 0 ? a4.x : (r == 1 ? a4.y : (r == 2 ? a4.z : a4.w));
        s[g][r] = c[g][r] * cs + av;
        tm = fmaxf(tm, s[g][r]);
      }
    }
    tm = fmaxf(tm, __shfl_xor(tm, 16));
    tm = fmaxf(tm, __shfl_xor(tm, 32));
    const float mnew = fmaxf(mrow, tm);
    const float alpha = exp2f(mrow - mnew);
    mrow = mnew;
    float p[4][4], rs = 0.f;
#pragma unroll
    for (int g = 0; g < 4; ++g)
#pragma unroll
      for (int r = 0; r < 4; ++r) {
        p[g][r] = exp2f(s[g][r] - mnew);
        rs += p[g][r];
      }
    rs += __shfl_xor(rs, 16);
    rs += __shfl_xor(rs, 32);
    lrow = lrow * alpha + rs;
#pragma unroll
    for (int mi = 0; mi < 4; mi++) o[mi] *= alpha;

    // pack P (bf16 pairs): dw[g][hh] = P^T[kv=g*16+quad*4+2hh..+1][q=l16]
    unsigned dw[4][2];
#pragma unroll
    for (int g = 0; g < 4; ++g) {
      dw[g][0] = pk(p[g][0], p[g][1]);
      dw[g][1] = pk(p[g][2], p[g][3]);
    }
    // in-register P^T -> B-frag transform
    const int qs0 = (quad & 1) * 2;
    const int src0 = l16 + 16 * qs0, src1 = src0 + 16;
    const bool hig = (quad >> 1) != 0;
#pragma unroll
    for (int ss = 0; ss < 2; ++ss) {
      const unsigned a0 = __shfl((int)dw[2 * ss][0], src0);
      const unsigned b0 = __shfl((int)dw[2 * ss + 1][0], src0);
      const unsigned a1 = __shfl((int)dw[2 * ss][1], src0);
      const unsigned b1 = __shfl((int)dw[2 * ss + 1][1], src0);
      const unsigned a2 = __shfl((int)dw[2 * ss][0], src1);
      const unsigned b2 = __shfl((int)dw[2 * ss + 1][0], src1);
      const unsigned a3 = __shfl((int)dw[2 * ss][1], src1);
      const unsigned b3 = __shfl((int)dw[2 * ss + 1][1], src1);
      uint4 du;
      du.x = hig ? b0 : a0;
      du.y = hig ? b1 : a1;
      du.z = hig ? b2 : a2;
      du.w = hig ? b3 : a3;
      const bf16x8 bp = *reinterpret_cast<bf16x8*>(&du);
#pragma unroll
      for (int mi = 0; mi < 4; ++mi) {
        const bf16x8 av = *(const bf16x8*)&lV[(mi * 16 + l16) * 64 +
                                              ((ss * 4 + quad) ^ (l16 & 7)) * 8];
        o[mi] = MFMA16(av, bp, o[mi]);
      }
    }
  }

  const float inv_l = 1.f / lrow;
  const long cb = ((long)b * 2048 + q0 + l16) * 1024 + h * 64;
#pragma unroll
  for (int mi = 0; mi < 4; mi++) {
    short4v w;
#pragma unroll
    for (int r = 0; r < 4; r++) w[r] = bf16bits(o[mi][r] * inv_l);
    *(short4v*)&ctx[cb + mi * 16 + quad * 4] = w;
  }
}

// ---------------------------------------------------------------------------
// ws plan (peak 32 MiB) + d_out (16 MiB) as scratch — identical to round 7:
//  A: wqkvT ws[24,30); ln1 x->xn(d_out[0,8) bf16); qkv-gemm -> qkv ws[0,24)
//  B: vtrans -> vtb ws[24,32); mask2add -> addm(d_out+12M, 16KB);
//     attn(qkv,vtb,addm) -> ctxb(d_out[0,8) bf16)
//  C: woT -> d_out[8,10); wo-gemm(ctxb,woT)+x -> x1 f32 ws[0,16)  (EPI1)
//  D: ln2 x1 -> xn2(d_out[0,8) bf16)
//  E c=0..1 (half=2048): w1Th -> d_out[8,12); ffn1(xn2,w1Th,+b1,relu)
//       -> hc ws[16,32) bf16; w2Th -> d_out[12,16);
//       ffn2: x1 += hc@w2Th^T (EPI3, K=2048)
//  F: bias_add: d_out = x1 + b2 (fp32)
// ---------------------------------------------------------------------------
extern "C" void kernel_launch(void* const* d_in, const int* in_sizes, int n_in,
                              void* d_out, int out_size, void* d_ws, size_t ws_size,
                              hipStream_t stream) {
  const float* x = (const float*)d_in[0];
  const int* mask = (const int*)d_in[1];
  const float* wq = (const float*)d_in[2];
  const float* wk = (const float*)d_in[3];
  const float* wv = (const float*)d_in[4];
  const float* wo = (const float*)d_in[5];
  const float* w1 = (const float*)d_in[6];
  const float* b1 = (const float*)d_in[7];
  const float* w2 = (const float*)d_in[8];
  const float* b2 = (const float*)d_in[9];
  const float* alpha1 = (const float*)d_in[10];
  const float* bias1 = (const float*)d_in[11];
  const float* alpha2 = (const float*)d_in[12];
  const float* bias2 = (const float*)d_in[13];

  char* ws = (char*)d_ws;
  char* dob = (char*)d_out;
  const size_t MiB = 1048576;
  __hip_bfloat16* qkv   = (__hip_bfloat16*)(ws + 0);          // [0,24)
  __hip_bfloat16* wqkvT = (__hip_bfloat16*)(ws + 24 * MiB);   // [24,30)
  __hip_bfloat16* vtb   = (__hip_bfloat16*)(ws + 24 * MiB);   // [24,32)
  float*          x1    = (float*)(ws + 0);                   // [0,16) f32
  __hip_bfloat16* hc    = (__hip_bfloat16*)(ws + 16 * MiB);   // [16,32)
  __hip_bfloat16* xn    = (__hip_bfloat16*)d_out;             // d_out[0,8) bf16
  __hip_bfloat16* ctxb  = (__hip_bfloat16*)d_out;
  __hip_bfloat16* xn2   = (__hip_bfloat16*)d_out;
  __hip_bfloat16* woT   = (__hip_bfloat16*)(dob + 8 * MiB);   // d_out[8,10)
  __hip_bfloat16* w1Th  = (__hip_bfloat16*)(dob + 8 * MiB);   // d_out[8,12)
  __hip_bfloat16* w2Th  = (__hip_bfloat16*)(dob + 12 * MiB);  // d_out[12,16)
  float*          addm  = (float*)(dob + 12 * MiB);           // d_out[12M,+16K)

  const dim3 b256(256);
  const dim3 g1k(16, 16);
  // Stage A
  transpose_f2b_kernel<<<g1k, b256, 0, stream>>>(wq, wqkvT, 1024, 1024, 1024);
  transpose_f2b_kernel<<<g1k, b256, 0, stream>>>(wk, wqkvT + 1024 * 1024, 1024, 1024, 1024);
  transpose_f2b_kernel<<<g1k, b256, 0, stream>>>(wv, wqkvT + 2 * 1024 * 1024, 1024, 1024, 1024);
  ln_kernel<<<4096, b256, 0, stream>>>(x, xn, alpha1, bias1);
  gemm_bt_kernel<0><<<dim3(24, 32), b256, 0, stream>>>(xn, wqkvT, qkv, nullptr, nullptr,
                                                       4096, 3072, 1024);
  // Stage B
  vtrans_kernel<<<dim3(32, 32), b256, 0, stream>>>(qkv, vtb);
  mask2add_kernel<<<16, b256, 0, stream>>>(mask, addm);
  attn_kernel<<<dim3(32, 32), b256, 0, stream>>>(qkv, vtb, addm, ctxb);
  // Stage C
  transpose_f2b_kernel<<<g1k, b256, 0, stream>>>(wo, woT, 1024, 1024, 1024);
  gemm_bt_kernel<1><<<dim3(8, 32), b256, 0, stream>>>(ctxb, woT, x1, nullptr, x,
                                                      4096, 1024, 1024);
  // Stage D
  ln_kernel<<<4096, b256, 0, stream>>>(x1, xn2, alpha2, bias2);
  // Stage E: FFN in 2 hidden-halves of 2048
  for (int c = 0; c < 2; ++c) {
    transpose_f2b_kernel<<<dim3(32, 16), b256, 0, stream>>>(w1 + c * 2048, w1Th,
                                                            1024, 2048, 4096);
    gemm_bt_kernel<2><<<dim3(16, 32), b256, 0, stream>>>(xn2, w1Th, hc, b1 + c * 2048,
                                                         nullptr, 4096, 2048, 1024);
    transpose_f2b_kernel<<<dim3(16, 32), b256, 0, stream>>>(w2 + (size_t)c * 2048 * 1024,
                                                            w2Th, 2048, 1024, 1024);
    gemm_bt_kernel<3><<<dim3(8, 32), b256, 0, stream>>>(hc, w2Th, x1, nullptr,
                                                        nullptr, 4096, 1024, 2048);
  }
  // Stage F
  bias_add_kernel<<<4096, b256, 0, stream>>>(x1, b2, (float*)d_out);
}

// Round 9
// 498.777 us; speedup vs baseline: 1.1777x; 1.1777x over previous
//
#include <hip/hip_runtime.h>
#include <hip/hip_bf16.h>

typedef __attribute__((ext_vector_type(8))) short bf16x8;
typedef __attribute__((ext_vector_type(4))) short short4v;
typedef __attribute__((ext_vector_type(4))) float floatx4;

#define MFMA16(A, B, C) __builtin_amdgcn_mfma_f32_16x16x32_bf16((A), (B), (C), 0, 0, 0)

__device__ inline short bf16bits(float f) {
  __hip_bfloat16 h = __float2bfloat16(f);
  return *reinterpret_cast<short*>(&h);
}
__device__ inline unsigned pk(float lo, float hi) {
  return (unsigned)(unsigned short)bf16bits(lo) |
         ((unsigned)(unsigned short)bf16bits(hi) << 16);
}
typedef __attribute__((address_space(3))) char lds_char;
typedef __attribute__((address_space(1))) const char glob_char;
__device__ inline void gll16(const void* g, void* l) {
  __builtin_amdgcn_global_load_lds((glob_char*)g, (lds_char*)l, 16, 0, 0);
}

// ---------------------------------------------------------------------------
// 64x64-tiled transpose, fp32 source -> bf16 dest: dst[c][r] = bf16(src[r*ldS+c])
// ---------------------------------------------------------------------------
__global__ __launch_bounds__(256) void transpose_f2b_kernel(
    const float* __restrict__ src, __hip_bfloat16* __restrict__ dst,
    int R, int C, int ldS) {
  __shared__ __align__(16) __hip_bfloat16 tile[64][72];
  const long r0 = (long)blockIdx.y * 64, c0 = (long)blockIdx.x * 64;
  for (int i = threadIdx.x; i < 1024; i += 256) {
    int r = i >> 4, c4 = (i & 15) * 4;
    float4 f = *(const float4*)&src[(r0 + r) * ldS + c0 + c4];
    short4v s;
    s[0] = bf16bits(f.x); s[1] = bf16bits(f.y);
    s[2] = bf16bits(f.z); s[3] = bf16bits(f.w);
    *(short4v*)&tile[r][c4] = s;
  }
  __syncthreads();
  for (int i = threadIdx.x; i < 512; i += 256) {
    int c = i >> 3, r8 = (i & 7) * 8;
    bf16x8 sv;
#pragma unroll
    for (int j = 0; j < 8; j++) sv[j] = *reinterpret_cast<const short*>(&tile[r8 + j][c]);
    *(bf16x8*)&dst[(c0 + c) * R + r0 + r8] = sv;
  }
}

// ---------------------------------------------------------------------------
// V transpose: qkv[B*S][3072] (bf16, V at col 2048 + h*64) -> vt[B*H][64][2048]
// ---------------------------------------------------------------------------
__global__ __launch_bounds__(256) void vtrans_kernel(
    const __hip_bfloat16* __restrict__ qkv, __hip_bfloat16* __restrict__ vt) {
  __shared__ __align__(16) __hip_bfloat16 tile[64][72];
  const int bh = blockIdx.y, b = bh >> 4, h = bh & 15;
  const long s0 = (long)blockIdx.x * 64;
  const __hip_bfloat16* src = qkv + ((long)b * 2048 + s0) * 3072 + 2048 + h * 64;
  for (int i = threadIdx.x; i < 512; i += 256) {
    int s = i >> 3, d8 = (i & 7) * 8;
    *(uint4*)&tile[s][d8] = *(const uint4*)&src[(long)s * 3072 + d8];
  }
  __syncthreads();
  __hip_bfloat16* dstb = vt + (long)bh * 64 * 2048 + s0;
  for (int i = threadIdx.x; i < 512; i += 256) {
    int d = i >> 3, s8 = (i & 7) * 8;
    bf16x8 sv;
#pragma unroll
    for (int j = 0; j < 8; j++) sv[j] = *reinterpret_cast<const short*>(&tile[s8 + j][d]);
    *(bf16x8*)&dstb[(long)d * 2048 + s8] = sv;
  }
}

// ---------------------------------------------------------------------------
// mask -> additive bias: 0 if mask!=0 else -1e30
// ---------------------------------------------------------------------------
__global__ __launch_bounds__(256) void mask2add_kernel(
    const int* __restrict__ mask, float* __restrict__ addm) {
  int i = blockIdx.x * 256 + threadIdx.x;
  addm[i] = mask[i] ? 0.f : -1e30f;
}

// ---------------------------------------------------------------------------
// d_out = x1 + b2 (broadcast over rows), fp32
// ---------------------------------------------------------------------------
__global__ __launch_bounds__(256) void bias_add_kernel(
    const float* __restrict__ x1, const float* __restrict__ b2,
    float* __restrict__ out) {
  const int i = (blockIdx.x * 256 + threadIdx.x) * 4;
  float4 v = *(const float4*)&x1[i];
  const float4 bb = *(const float4*)&b2[i & 1023];
  v.x += bb.x; v.y += bb.y; v.z += bb.z; v.w += bb.w;
  *(float4*)&out[i] = v;
}

// ---------------------------------------------------------------------------
// LayerNorm: 1 block per 1024-elem row. ddof=1, eps added to std. fp32 -> bf16.
// ---------------------------------------------------------------------------
__global__ __launch_bounds__(256) void ln_kernel(
    const float* __restrict__ x, __hip_bfloat16* __restrict__ y,
    const float* __restrict__ alpha_p, const float* __restrict__ bias_p) {
  __shared__ float sred[8];
  const long row = blockIdx.x;
  const int t = threadIdx.x;
  const float* xr = x + row * 1024;
  float v[4];
#pragma unroll
  for (int i = 0; i < 4; i++) v[i] = xr[t * 4 + i];
  float sum = 0.f, sq = 0.f;
#pragma unroll
  for (int i = 0; i < 4; i++) { sum += v[i]; sq += v[i] * v[i]; }
#pragma unroll
  for (int off = 32; off; off >>= 1) {
    sum += __shfl_down(sum, off);
    sq += __shfl_down(sq, off);
  }
  if ((t & 63) == 0) { sred[(t >> 6) * 2] = sum; sred[(t >> 6) * 2 + 1] = sq; }
  __syncthreads();
  sum = sred[0] + sred[2] + sred[4] + sred[6];
  sq = sred[1] + sred[3] + sred[5] + sred[7];
  const float mean = sum * (1.f / 1024.f);
  float var = (sq - 1024.f * mean * mean) * (1.f / 1023.f);
  var = fmaxf(var, 0.f);
  const float denom = sqrtf(var) + 1e-5f;
  const float sc = alpha_p[0] / denom;
  const float beta = bias_p[0];
  __hip_bfloat16* yr = y + row * 1024;
#pragma unroll
  for (int i = 0; i < 4; i++) yr[t * 4 + i] = __float2bfloat16((v[i] - mean) * sc + beta);
}

// ---------------------------------------------------------------------------
// bf16 GEMM, B pre-transposed: C[M][N] = A[M][K] @ Bt[N][K]^T
// m97-style staging: global_load_lds width=16.
// EPI: 0 = bf16 store; 1 = (+f32 res)->f32; 2 = (+bias, relu)->bf16;
//      3 = f32 C += v
// ---------------------------------------------------------------------------
template <int EPI>
__global__ __launch_bounds__(256) void gemm_bt_kernel(
    const __hip_bfloat16* __restrict__ A, const __hip_bfloat16* __restrict__ Bt,
    void* __restrict__ Cv, const float* __restrict__ bias,
    const float* __restrict__ res, int M, int N, int K) {
  __shared__ __align__(16) __hip_bfloat16 lA[128 * 32];
  __shared__ __align__(16) __hip_bfloat16 lB[128 * 32];
  const int tid = threadIdx.x;
  const int wave = tid >> 6, lane = tid & 63;
  const int quad = lane >> 4, l16 = lane & 15;
  const int wm = wave >> 1, wn = wave & 1;
  const long m0 = (long)blockIdx.y * 128;
  const long n0 = (long)blockIdx.x * 128;

  const int rA0 = tid >> 2, cA0 = (tid & 3) * 8;
  const int rA1 = (tid + 256) >> 2, cA1 = ((tid + 256) & 3) * 8;

  floatx4 acc[4][4];
#pragma unroll
  for (int i = 0; i < 4; i++)
#pragma unroll
    for (int j = 0; j < 4; j++) acc[i][j] = (floatx4){0.f, 0.f, 0.f, 0.f};

  const __hip_bfloat16* Ab = A + m0 * K;
  const __hip_bfloat16* Bb = Bt + n0 * K;

  for (int k0 = 0; k0 < K; k0 += 32) {
    __syncthreads();
    gll16(&Ab[(long)rA0 * K + k0 + cA0], &lA[wave * 512]);
    gll16(&Ab[(long)rA1 * K + k0 + cA1], &lA[2048 + wave * 512]);
    gll16(&Bb[(long)rA0 * K + k0 + cA0], &lB[wave * 512]);
    gll16(&Bb[(long)rA1 * K + k0 + cA1], &lB[2048 + wave * 512]);
    __syncthreads();
    bf16x8 af[4], bfr[4];
#pragma unroll
    for (int mi = 0; mi < 4; mi++)
      af[mi] = *(const bf16x8*)&lA[(wm * 64 + mi * 16 + l16) * 32 + quad * 8];
#pragma unroll
    for (int ni = 0; ni < 4; ni++)
      bfr[ni] = *(const bf16x8*)&lB[(wn * 64 + ni * 16 + l16) * 32 + quad * 8];
#pragma unroll
    for (int mi = 0; mi < 4; mi++)
#pragma unroll
      for (int ni = 0; ni < 4; ni++)
        acc[mi][ni] = MFMA16(af[mi], bfr[ni], acc[mi][ni]);
  }

#pragma unroll
  for (int mi = 0; mi < 4; mi++) {
#pragma unroll
    for (int ni = 0; ni < 4; ni++) {
#pragma unroll
      for (int r = 0; r < 4; r++) {
        const long row = m0 + wm * 64 + mi * 16 + quad * 4 + r;
        const long col = n0 + wn * 64 + ni * 16 + l16;
        const long idx = row * N + col;
        float v = acc[mi][ni][r];
        if (EPI == 0) {
          ((__hip_bfloat16*)Cv)[idx] = __float2bfloat16(v);
        } else if (EPI == 1) {
          ((float*)Cv)[idx] = v + res[idx];
        } else if (EPI == 2) {
          v += bias[col];
          ((__hip_bfloat16*)Cv)[idx] = __float2bfloat16(fmaxf(v, 0.f));
        } else if (EPI == 3) {
          float* Cf = (float*)Cv;
          Cf[idx] = Cf[idx] + v;
        }
      }
    }
  }
}

// ---------------------------------------------------------------------------
// Flash attention (round-6 verified version): block = 4 waves, one (b,h),
// 64 queries. K/V tiles staged via global_load_lds into a SINGLE buffer with
// the m97-verified two-barrier shape. No register prefetch, no launch_bounds
// min-waves hint — both variants (r7 prefetch, r8 +(256,4)) made the compiler
// spill to scratch (WRITE_SIZE 8->299/428 MB, attn 115->185/188 us).
// XOR-swizzled LDS, register-shfl P^T, additive mask. 115 us, VGPR 60.
// ---------------------------------------------------------------------------
__global__ __launch_bounds__(256) void attn_kernel(
    const __hip_bfloat16* __restrict__ qkv, const __hip_bfloat16* __restrict__ vt,
    const float* __restrict__ addm, __hip_bfloat16* __restrict__ ctx) {
  __shared__ __align__(16) __hip_bfloat16 lK[64 * 64];
  __shared__ __align__(16) __hip_bfloat16 lV[64 * 64];
  const int tid = threadIdx.x, wave = tid >> 6, lane = tid & 63;
  const int quad = lane >> 4, l16 = lane & 15;
  const int bh = blockIdx.y, b = bh >> 4, h = bh & 15;
  const int q0 = blockIdx.x * 64 + wave * 16;
  const float cs = 0.18033688011112042f;  // log2(e)/sqrt(64)

  const __hip_bfloat16* kb = qkv + (long)b * 2048 * 3072 + 1024 + h * 64;
  const __hip_bfloat16* vb = vt + (long)bh * 64 * 2048;
  const float* am = addm + b * 2048;

  // Q B-frags: Q[q=l16][kd=quad*8+j]
  const long qoff = ((long)b * 2048 + q0 + l16) * 3072 + h * 64;
  const bf16x8 bq0 = *(const bf16x8*)&qkv[qoff + quad * 8];
  const bf16x8 bq1 = *(const bf16x8*)&qkv[qoff + 32 + quad * 8];

  // staging: lane -> (row = j*8 + lane/8, LDS slot = lane&7), chunk = slot^(row&7)
  const int srow = lane >> 3;
  const int cslot = lane & 7;
  const int cg = cslot ^ srow;

  floatx4 o[4];
#pragma unroll
  for (int mi = 0; mi < 4; mi++) o[mi] = (floatx4){0.f, 0.f, 0.f, 0.f};
  float mrow = -3.0e38f, lrow = 0.f;

  for (int t = 0; t < 32; ++t) {
    __syncthreads();  // WAR: all waves done reading tile t-1
#pragma unroll
    for (int j = 0; j < 2; ++j) {
      const int rloc = wave * 16 + j * 8 + srow;
      gll16(kb + (long)(t * 64 + rloc) * 3072 + cg * 8,
            &lK[(wave * 16 + j * 8) * 64]);
      gll16(vb + (long)rloc * 2048 + t * 64 + cg * 8,
            &lV[(wave * 16 + j * 8) * 64]);
    }
    __syncthreads();  // RAW: staging complete (vmcnt drained before barrier)

    // S^T: 4 groups of 16 kv rows
    floatx4 c[4];
#pragma unroll
    for (int g = 0; g < 4; ++g) {
      const bf16x8 a0 =
          *(const bf16x8*)&lK[(g * 16 + l16) * 64 + ((quad) ^ (l16 & 7)) * 8];
      const bf16x8 a1 =
          *(const bf16x8*)&lK[(g * 16 + l16) * 64 + ((4 + quad) ^ (l16 & 7)) * 8];
      floatx4 cc = {0.f, 0.f, 0.f, 0.f};
      cc = MFMA16(a0, bq0, cc);
      cc = MFMA16(a1, bq1, cc);
      c[g] = cc;
    }
    // scores (log2 domain) + additive mask
    float s[4][4];
    float tm = -3.0e38f;
#pragma unroll
    for (int g = 0; g < 4; ++g) {
      const float4 a4 = *(const float4*)&am[t * 64 + g * 16 + quad * 4];
#pragma unroll
      for (int r = 0; r < 4; ++r) {
        const float av = r == 0 ? a4.x : (r == 1 ? a4.y : (r == 2 ? a4.z : a4.w));
        s[g][r] = c[g][r] * cs + av;
        tm = fmaxf(tm, s[g][r]);
      }
    }
    tm = fmaxf(tm, __shfl_xor(tm, 16));
    tm = fmaxf(tm, __shfl_xor(tm, 32));
    const float mnew = fmaxf(mrow, tm);
    const float alpha = exp2f(mrow - mnew);
    mrow = mnew;
    float p[4][4], rs = 0.f;
#pragma unroll
    for (int g = 0; g < 4; ++g)
#pragma unroll
      for (int r = 0; r < 4; ++r) {
        p[g][r] = exp2f(s[g][r] - mnew);
        rs += p[g][r];
      }
    rs += __shfl_xor(rs, 16);
    rs += __shfl_xor(rs, 32);
    lrow = lrow * alpha + rs;
#pragma unroll
    for (int mi = 0; mi < 4; mi++) o[mi] *= alpha;

    // pack P (bf16 pairs): dw[g][hh] = P^T[kv=g*16+quad*4+2hh..+1][q=l16]
    unsigned dw[4][2];
#pragma unroll
    for (int g = 0; g < 4; ++g) {
      dw[g][0] = pk(p[g][0], p[g][1]);
      dw[g][1] = pk(p[g][2], p[g][3]);
    }
    // in-register P^T -> B-frag transform
    const int qs0 = (quad & 1) * 2;
    const int src0 = l16 + 16 * qs0, src1 = src0 + 16;
    const bool hig = (quad >> 1) != 0;
#pragma unroll
    for (int ss = 0; ss < 2; ++ss) {
      const unsigned a0 = __shfl((int)dw[2 * ss][0], src0);
      const unsigned b0 = __shfl((int)dw[2 * ss + 1][0], src0);
      const unsigned a1 = __shfl((int)dw[2 * ss][1], src0);
      const unsigned b1 = __shfl((int)dw[2 * ss + 1][1], src0);
      const unsigned a2 = __shfl((int)dw[2 * ss][0], src1);
      const unsigned b2 = __shfl((int)dw[2 * ss + 1][0], src1);
      const unsigned a3 = __shfl((int)dw[2 * ss][1], src1);
      const unsigned b3 = __shfl((int)dw[2 * ss + 1][1], src1);
      uint4 du;
      du.x = hig ? b0 : a0;
      du.y = hig ? b1 : a1;
      du.z = hig ? b2 : a2;
      du.w = hig ? b3 : a3;
      const bf16x8 bp = *reinterpret_cast<bf16x8*>(&du);
#pragma unroll
      for (int mi = 0; mi < 4; ++mi) {
        const bf16x8 av = *(const bf16x8*)&lV[(mi * 16 + l16) * 64 +
                                              ((ss * 4 + quad) ^ (l16 & 7)) * 8];
        o[mi] = MFMA16(av, bp, o[mi]);
      }
    }
  }

  const float inv_l = 1.f / lrow;
  const long cb = ((long)b * 2048 + q0 + l16) * 1024 + h * 64;
#pragma unroll
  for (int mi = 0; mi < 4; mi++) {
    short4v w;
#pragma unroll
    for (int r = 0; r < 4; r++) w[r] = bf16bits(o[mi][r] * inv_l);
    *(short4v*)&ctx[cb + mi * 16 + quad * 4] = w;
  }
}

// ---------------------------------------------------------------------------
// ws plan (peak 32 MiB) + d_out (16 MiB) as scratch — identical to round 7/8:
//  A: wqkvT ws[24,30); ln1 x->xn(d_out[0,8) bf16); qkv-gemm -> qkv ws[0,24)
//  B: vtrans -> vtb ws[24,32); mask2add -> addm(d_out+12M, 16KB);
//     attn(qkv,vtb,addm) -> ctxb(d_out[0,8) bf16)
//  C: woT -> d_out[8,10); wo-gemm(ctxb,woT)+x -> x1 f32 ws[0,16)  (EPI1)
//  D: ln2 x1 -> xn2(d_out[0,8) bf16)
//  E c=0..1 (half=2048): w1Th -> d_out[8,12); ffn1(xn2,w1Th,+b1,relu)
//       -> hc ws[16,32) bf16; w2Th -> d_out[12,16);
//       ffn2: x1 += hc@w2Th^T (EPI3, K=2048)
//  F: bias_add: d_out = x1 + b2 (fp32)
// ---------------------------------------------------------------------------
extern "C" void kernel_launch(void* const* d_in, const int* in_sizes, int n_in,
                              void* d_out, int out_size, void* d_ws, size_t ws_size,
                              hipStream_t stream) {
  const float* x = (const float*)d_in[0];
  const int* mask = (const int*)d_in[1];
  const float* wq = (const float*)d_in[2];
  const float* wk = (const float*)d_in[3];
  const float* wv = (const float*)d_in[4];
  const float* wo = (const float*)d_in[5];
  const float* w1 = (const float*)d_in[6];
  const float* b1 = (const float*)d_in[7];
  const float* w2 = (const float*)d_in[8];
  const float* b2 = (const float*)d_in[9];
  const float* alpha1 = (const float*)d_in[10];
  const float* bias1 = (const float*)d_in[11];
  const float* alpha2 = (const float*)d_in[12];
  const float* bias2 = (const float*)d_in[13];

  char* ws = (char*)d_ws;
  char* dob = (char*)d_out;
  const size_t MiB = 1048576;
  __hip_bfloat16* qkv   = (__hip_bfloat16*)(ws + 0);          // [0,24)
  __hip_bfloat16* wqkvT = (__hip_bfloat16*)(ws + 24 * MiB);   // [24,30)
  __hip_bfloat16* vtb   = (__hip_bfloat16*)(ws + 24 * MiB);   // [24,32)
  float*          x1    = (float*)(ws + 0);                   // [0,16) f32
  __hip_bfloat16* hc    = (__hip_bfloat16*)(ws + 16 * MiB);   // [16,32)
  __hip_bfloat16* xn    = (__hip_bfloat16*)d_out;             // d_out[0,8) bf16
  __hip_bfloat16* ctxb  = (__hip_bfloat16*)d_out;
  __hip_bfloat16* xn2   = (__hip_bfloat16*)d_out;
  __hip_bfloat16* woT   = (__hip_bfloat16*)(dob + 8 * MiB);   // d_out[8,10)
  __hip_bfloat16* w1Th  = (__hip_bfloat16*)(dob + 8 * MiB);   // d_out[8,12)
  __hip_bfloat16* w2Th  = (__hip_bfloat16*)(dob + 12 * MiB);  // d_out[12,16)
  float*          addm  = (float*)(dob + 12 * MiB);           // d_out[12M,+16K)

  const dim3 b256(256);
  const dim3 g1k(16, 16);
  // Stage A
  transpose_f2b_kernel<<<g1k, b256, 0, stream>>>(wq, wqkvT, 1024, 1024, 1024);
  transpose_f2b_kernel<<<g1k, b256, 0, stream>>>(wk, wqkvT + 1024 * 1024, 1024, 1024, 1024);
  transpose_f2b_kernel<<<g1k, b256, 0, stream>>>(wv, wqkvT + 2 * 1024 * 1024, 1024, 1024, 1024);
  ln_kernel<<<4096, b256, 0, stream>>>(x, xn, alpha1, bias1);
  gemm_bt_kernel<0><<<dim3(24, 32), b256, 0, stream>>>(xn, wqkvT, qkv, nullptr, nullptr,
                                                       4096, 3072, 1024);
  // Stage B
  vtrans_kernel<<<dim3(32, 32), b256, 0, stream>>>(qkv, vtb);
  mask2add_kernel<<<16, b256, 0, stream>>>(mask, addm);
  attn_kernel<<<dim3(32, 32), b256, 0, stream>>>(qkv, vtb, addm, ctxb);
  // Stage C
  transpose_f2b_kernel<<<g1k, b256, 0, stream>>>(wo, woT, 1024, 1024, 1024);
  gemm_bt_kernel<1><<<dim3(8, 32), b256, 0, stream>>>(ctxb, woT, x1, nullptr, x,
                                                      4096, 1024, 1024);
  // Stage D
  ln_kernel<<<4096, b256, 0, stream>>>(x1, xn2, alpha2, bias2);
  // Stage E: FFN in 2 hidden-halves of 2048
  for (int c = 0; c < 2; ++c) {
    transpose_f2b_kernel<<<dim3(32, 16), b256, 0, stream>>>(w1 + c * 2048, w1Th,
                                                            1024, 2048, 4096);
    gemm_bt_kernel<2><<<dim3(16, 32), b256, 0, stream>>>(xn2, w1Th, hc, b1 + c * 2048,
                                                         nullptr, 4096, 2048, 1024);
    transpose_f2b_kernel<<<dim3(16, 32), b256, 0, stream>>>(w2 + (size_t)c * 2048 * 1024,
                                                            w2Th, 2048, 1024, 1024);
    gemm_bt_kernel<3><<<dim3(8, 32), b256, 0, stream>>>(hc, w2Th, x1, nullptr,
                                                        nullptr, 4096, 1024, 2048);
  }
  // Stage F
  bias_add_kernel<<<4096, b256, 0, stream>>>(x1, b2, (float*)d_out);
}

// Round 10
// 482.878 us; speedup vs baseline: 1.2164x; 1.0329x over previous
//
#include <hip/hip_runtime.h>
#include <hip/hip_bf16.h>

typedef __attribute__((ext_vector_type(8))) short bf16x8;
typedef __attribute__((ext_vector_type(4))) short short4v;
typedef __attribute__((ext_vector_type(4))) float floatx4;

#define MFMA16(A, B, C) __builtin_amdgcn_mfma_f32_16x16x32_bf16((A), (B), (C), 0, 0, 0)

__device__ inline short bf16bits(float f) {
  __hip_bfloat16 h = __float2bfloat16(f);
  return *reinterpret_cast<short*>(&h);
}
__device__ inline unsigned pk(float lo, float hi) {
  return (unsigned)(unsigned short)bf16bits(lo) |
         ((unsigned)(unsigned short)bf16bits(hi) << 16);
}
typedef __attribute__((address_space(3))) char lds_char;
typedef __attribute__((address_space(1))) const char glob_char;
__device__ inline void gll16(const void* g, void* l) {
  __builtin_amdgcn_global_load_lds((glob_char*)g, (lds_char*)l, 16, 0, 0);
}

// ---------------------------------------------------------------------------
// 64x64-tiled transpose, fp32 source -> bf16 dest: dst[c][r] = bf16(src[r*ldS+c])
// ---------------------------------------------------------------------------
__global__ __launch_bounds__(256) void transpose_f2b_kernel(
    const float* __restrict__ src, __hip_bfloat16* __restrict__ dst,
    int R, int C, int ldS) {
  __shared__ __align__(16) __hip_bfloat16 tile[64][72];
  const long r0 = (long)blockIdx.y * 64, c0 = (long)blockIdx.x * 64;
  for (int i = threadIdx.x; i < 1024; i += 256) {
    int r = i >> 4, c4 = (i & 15) * 4;
    float4 f = *(const float4*)&src[(r0 + r) * ldS + c0 + c4];
    short4v s;
    s[0] = bf16bits(f.x); s[1] = bf16bits(f.y);
    s[2] = bf16bits(f.z); s[3] = bf16bits(f.w);
    *(short4v*)&tile[r][c4] = s;
  }
  __syncthreads();
  for (int i = threadIdx.x; i < 512; i += 256) {
    int c = i >> 3, r8 = (i & 7) * 8;
    bf16x8 sv;
#pragma unroll
    for (int j = 0; j < 8; j++) sv[j] = *reinterpret_cast<const short*>(&tile[r8 + j][c]);
    *(bf16x8*)&dst[(c0 + c) * R + r0 + r8] = sv;
  }
}

// ---------------------------------------------------------------------------
// Merged wq/wk/wv transpose: grid (16, 48); by/16 selects the weight, writes
// wqkvT + which*1M. All three are 1024x1024, ldS=1024.
// ---------------------------------------------------------------------------
__global__ __launch_bounds__(256) void transpose_qkv_kernel(
    const float* __restrict__ wq, const float* __restrict__ wk,
    const float* __restrict__ wv, __hip_bfloat16* __restrict__ wqkvT) {
  __shared__ __align__(16) __hip_bfloat16 tile[64][72];
  const int which = blockIdx.y >> 4;
  const float* src = which == 0 ? wq : (which == 1 ? wk : wv);
  __hip_bfloat16* dst = wqkvT + (size_t)which * 1024 * 1024;
  const long r0 = (long)(blockIdx.y & 15) * 64, c0 = (long)blockIdx.x * 64;
  for (int i = threadIdx.x; i < 1024; i += 256) {
    int r = i >> 4, c4 = (i & 15) * 4;
    float4 f = *(const float4*)&src[(r0 + r) * 1024 + c0 + c4];
    short4v s;
    s[0] = bf16bits(f.x); s[1] = bf16bits(f.y);
    s[2] = bf16bits(f.z); s[3] = bf16bits(f.w);
    *(short4v*)&tile[r][c4] = s;
  }
  __syncthreads();
  for (int i = threadIdx.x; i < 512; i += 256) {
    int c = i >> 3, r8 = (i & 7) * 8;
    bf16x8 sv;
#pragma unroll
    for (int j = 0; j < 8; j++) sv[j] = *reinterpret_cast<const short*>(&tile[r8 + j][c]);
    *(bf16x8*)&dst[(c0 + c) * 1024 + r0 + r8] = sv;
  }
}

// ---------------------------------------------------------------------------
// V transpose: qkv[B*S][3072] (bf16, V at col 2048 + h*64) -> vt[B*H][64][2048]
// ---------------------------------------------------------------------------
__global__ __launch_bounds__(256) void vtrans_kernel(
    const __hip_bfloat16* __restrict__ qkv, __hip_bfloat16* __restrict__ vt) {
  __shared__ __align__(16) __hip_bfloat16 tile[64][72];
  const int bh = blockIdx.y, b = bh >> 4, h = bh & 15;
  const long s0 = (long)blockIdx.x * 64;
  const __hip_bfloat16* src = qkv + ((long)b * 2048 + s0) * 3072 + 2048 + h * 64;
  for (int i = threadIdx.x; i < 512; i += 256) {
    int s = i >> 3, d8 = (i & 7) * 8;
    *(uint4*)&tile[s][d8] = *(const uint4*)&src[(long)s * 3072 + d8];
  }
  __syncthreads();
  __hip_bfloat16* dstb = vt + (long)bh * 64 * 2048 + s0;
  for (int i = threadIdx.x; i < 512; i += 256) {
    int d = i >> 3, s8 = (i & 7) * 8;
    bf16x8 sv;
#pragma unroll
    for (int j = 0; j < 8; j++) sv[j] = *reinterpret_cast<const short*>(&tile[s8 + j][d]);
    *(bf16x8*)&dstb[(long)d * 2048 + s8] = sv;
  }
}

// ---------------------------------------------------------------------------
// mask -> additive bias: 0 if mask!=0 else -1e30
// ---------------------------------------------------------------------------
__global__ __launch_bounds__(256) void mask2add_kernel(
    const int* __restrict__ mask, float* __restrict__ addm) {
  int i = blockIdx.x * 256 + threadIdx.x;
  addm[i] = mask[i] ? 0.f : -1e30f;
}

// ---------------------------------------------------------------------------
// d_out = x1 + b2 (broadcast over rows), fp32
// ---------------------------------------------------------------------------
__global__ __launch_bounds__(256) void bias_add_kernel(
    const float* __restrict__ x1, const float* __restrict__ b2,
    float* __restrict__ out) {
  const int i = (blockIdx.x * 256 + threadIdx.x) * 4;
  float4 v = *(const float4*)&x1[i];
  const float4 bb = *(const float4*)&b2[i & 1023];
  v.x += bb.x; v.y += bb.y; v.z += bb.z; v.w += bb.w;
  *(float4*)&out[i] = v;
}

// ---------------------------------------------------------------------------
// LayerNorm: 1 block per 1024-elem row. ddof=1, eps added to std. fp32 -> bf16.
// ---------------------------------------------------------------------------
__global__ __launch_bounds__(256) void ln_kernel(
    const float* __restrict__ x, __hip_bfloat16* __restrict__ y,
    const float* __restrict__ alpha_p, const float* __restrict__ bias_p) {
  __shared__ float sred[8];
  const long row = blockIdx.x;
  const int t = threadIdx.x;
  const float* xr = x + row * 1024;
  float v[4];
#pragma unroll
  for (int i = 0; i < 4; i++) v[i] = xr[t * 4 + i];
  float sum = 0.f, sq = 0.f;
#pragma unroll
  for (int i = 0; i < 4; i++) { sum += v[i]; sq += v[i] * v[i]; }
#pragma unroll
  for (int off = 32; off; off >>= 1) {
    sum += __shfl_down(sum, off);
    sq += __shfl_down(sq, off);
  }
  if ((t & 63) == 0) { sred[(t >> 6) * 2] = sum; sred[(t >> 6) * 2 + 1] = sq; }
  __syncthreads();
  sum = sred[0] + sred[2] + sred[4] + sred[6];
  sq = sred[1] + sred[3] + sred[5] + sred[7];
  const float mean = sum * (1.f / 1024.f);
  float var = (sq - 1024.f * mean * mean) * (1.f / 1023.f);
  var = fmaxf(var, 0.f);
  const float denom = sqrtf(var) + 1e-5f;
  const float sc = alpha_p[0] / denom;
  const float beta = bias_p[0];
  __hip_bfloat16* yr = y + row * 1024;
#pragma unroll
  for (int i = 0; i < 4; i++) yr[t * 4 + i] = __float2bfloat16((v[i] - mean) * sc + beta);
}

// ---------------------------------------------------------------------------
// bf16 GEMM, B pre-transposed: C[M][N] = A[M][K] @ Bt[N][K]^T
// 128x128 tile, m97-style gll16 staging.
// EPI: 0 = bf16 store; 1 = (+f32 res)->f32; 2 = (+bias, relu)->bf16;
//      3 = f32 C += v
// ---------------------------------------------------------------------------
template <int EPI>
__global__ __launch_bounds__(256) void gemm_bt_kernel(
    const __hip_bfloat16* __restrict__ A, const __hip_bfloat16* __restrict__ Bt,
    void* __restrict__ Cv, const float* __restrict__ bias,
    const float* __restrict__ res, int M, int N, int K) {
  __shared__ __align__(16) __hip_bfloat16 lA[128 * 32];
  __shared__ __align__(16) __hip_bfloat16 lB[128 * 32];
  const int tid = threadIdx.x;
  const int wave = tid >> 6, lane = tid & 63;
  const int quad = lane >> 4, l16 = lane & 15;
  const int wm = wave >> 1, wn = wave & 1;
  const long m0 = (long)blockIdx.y * 128;
  const long n0 = (long)blockIdx.x * 128;

  const int rA0 = tid >> 2, cA0 = (tid & 3) * 8;
  const int rA1 = (tid + 256) >> 2, cA1 = ((tid + 256) & 3) * 8;

  floatx4 acc[4][4];
#pragma unroll
  for (int i = 0; i < 4; i++)
#pragma unroll
    for (int j = 0; j < 4; j++) acc[i][j] = (floatx4){0.f, 0.f, 0.f, 0.f};

  const __hip_bfloat16* Ab = A + m0 * K;
  const __hip_bfloat16* Bb = Bt + n0 * K;

  for (int k0 = 0; k0 < K; k0 += 32) {
    __syncthreads();
    gll16(&Ab[(long)rA0 * K + k0 + cA0], &lA[wave * 512]);
    gll16(&Ab[(long)rA1 * K + k0 + cA1], &lA[2048 + wave * 512]);
    gll16(&Bb[(long)rA0 * K + k0 + cA0], &lB[wave * 512]);
    gll16(&Bb[(long)rA1 * K + k0 + cA1], &lB[2048 + wave * 512]);
    __syncthreads();
    bf16x8 af[4], bfr[4];
#pragma unroll
    for (int mi = 0; mi < 4; mi++)
      af[mi] = *(const bf16x8*)&lA[(wm * 64 + mi * 16 + l16) * 32 + quad * 8];
#pragma unroll
    for (int ni = 0; ni < 4; ni++)
      bfr[ni] = *(const bf16x8*)&lB[(wn * 64 + ni * 16 + l16) * 32 + quad * 8];
#pragma unroll
    for (int mi = 0; mi < 4; mi++)
#pragma unroll
      for (int ni = 0; ni < 4; ni++)
        acc[mi][ni] = MFMA16(af[mi], bfr[ni], acc[mi][ni]);
  }

#pragma unroll
  for (int mi = 0; mi < 4; mi++) {
#pragma unroll
    for (int ni = 0; ni < 4; ni++) {
#pragma unroll
      for (int r = 0; r < 4; r++) {
        const long row = m0 + wm * 64 + mi * 16 + quad * 4 + r;
        const long col = n0 + wn * 64 + ni * 16 + l16;
        const long idx = row * N + col;
        float v = acc[mi][ni][r];
        if (EPI == 0) {
          ((__hip_bfloat16*)Cv)[idx] = __float2bfloat16(v);
        } else if (EPI == 1) {
          ((float*)Cv)[idx] = v + res[idx];
        } else if (EPI == 2) {
          v += bias[col];
          ((__hip_bfloat16*)Cv)[idx] = __float2bfloat16(fmaxf(v, 0.f));
        } else if (EPI == 3) {
          float* Cf = (float*)Cv;
          Cf[idx] = Cf[idx] + v;
        }
      }
    }
  }
}

// ---------------------------------------------------------------------------
// 128x64-tile variant for N=1024 GEMMs (wo, ffn2): grid doubles to 512 blocks
// = 2 blocks/CU (the 128x128 version gave 1/CU — barrier drain fully exposed,
// m114 overlap needs co-resident blocks). 4 waves as 2x2 over (128,64); each
// wave 64x32 (acc 4x2). LDS 12 KB.
// ---------------------------------------------------------------------------
template <int EPI>
__global__ __launch_bounds__(256) void gemm64_bt_kernel(
    const __hip_bfloat16* __restrict__ A, const __hip_bfloat16* __restrict__ Bt,
    void* __restrict__ Cv, const float* __restrict__ bias,
    const float* __restrict__ res, int M, int N, int K) {
  __shared__ __align__(16) __hip_bfloat16 lA[128 * 32];
  __shared__ __align__(16) __hip_bfloat16 lB[64 * 32];
  const int tid = threadIdx.x;
  const int wave = tid >> 6, lane = tid & 63;
  const int quad = lane >> 4, l16 = lane & 15;
  const int wm = wave >> 1, wn = wave & 1;
  const long m0 = (long)blockIdx.y * 128;
  const long n0 = (long)blockIdx.x * 64;

  const int rA0 = tid >> 2, cA0 = (tid & 3) * 8;
  const int rA1 = (tid + 256) >> 2, cA1 = ((tid + 256) & 3) * 8;

  floatx4 acc[4][2];
#pragma unroll
  for (int i = 0; i < 4; i++)
#pragma unroll
    for (int j = 0; j < 2; j++) acc[i][j] = (floatx4){0.f, 0.f, 0.f, 0.f};

  const __hip_bfloat16* Ab = A + m0 * K;
  const __hip_bfloat16* Bb = Bt + n0 * K;

  for (int k0 = 0; k0 < K; k0 += 32) {
    __syncthreads();
    gll16(&Ab[(long)rA0 * K + k0 + cA0], &lA[wave * 512]);
    gll16(&Ab[(long)rA1 * K + k0 + cA1], &lA[2048 + wave * 512]);
    gll16(&Bb[(long)rA0 * K + k0 + cA0], &lB[wave * 512]);
    __syncthreads();
    bf16x8 af[4], bfr[2];
#pragma unroll
    for (int mi = 0; mi < 4; mi++)
      af[mi] = *(const bf16x8*)&lA[(wm * 64 + mi * 16 + l16) * 32 + quad * 8];
#pragma unroll
    for (int ni = 0; ni < 2; ni++)
      bfr[ni] = *(const bf16x8*)&lB[(wn * 32 + ni * 16 + l16) * 32 + quad * 8];
#pragma unroll
    for (int mi = 0; mi < 4; mi++)
#pragma unroll
      for (int ni = 0; ni < 2; ni++)
        acc[mi][ni] = MFMA16(af[mi], bfr[ni], acc[mi][ni]);
  }

#pragma unroll
  for (int mi = 0; mi < 4; mi++) {
#pragma unroll
    for (int ni = 0; ni < 2; ni++) {
#pragma unroll
      for (int r = 0; r < 4; r++) {
        const long row = m0 + wm * 64 + mi * 16 + quad * 4 + r;
        const long col = n0 + wn * 32 + ni * 16 + l16;
        const long idx = row * N + col;
        float v = acc[mi][ni][r];
        if (EPI == 1) {
          ((float*)Cv)[idx] = v + res[idx];
        } else if (EPI == 3) {
          float* Cf = (float*)Cv;
          Cf[idx] = Cf[idx] + v;
        }
      }
    }
  }
}

// ---------------------------------------------------------------------------
// Flash attention (round-6 verified version, untouched): 111 us, VGPR 60,
// zero spill. gll16 two-barrier single-buffer; XOR-swizzled LDS; register-shfl
// P^T; additive mask. (r7 prefetch / r8 launch_bounds hint both made the
// compiler spill — WRITE_SIZE 8 -> 299/428 MB. Do not reintroduce.)
// ---------------------------------------------------------------------------
__global__ __launch_bounds__(256) void attn_kernel(
    const __hip_bfloat16* __restrict__ qkv, const __hip_bfloat16* __restrict__ vt,
    const float* __restrict__ addm, __hip_bfloat16* __restrict__ ctx) {
  __shared__ __align__(16) __hip_bfloat16 lK[64 * 64];
  __shared__ __align__(16) __hip_bfloat16 lV[64 * 64];
  const int tid = threadIdx.x, wave = tid >> 6, lane = tid & 63;
  const int quad = lane >> 4, l16 = lane & 15;
  const int bh = blockIdx.y, b = bh >> 4, h = bh & 15;
  const int q0 = blockIdx.x * 64 + wave * 16;
  const float cs = 0.18033688011112042f;  // log2(e)/sqrt(64)

  const __hip_bfloat16* kb = qkv + (long)b * 2048 * 3072 + 1024 + h * 64;
  const __hip_bfloat16* vb = vt + (long)bh * 64 * 2048;
  const float* am = addm + b * 2048;

  const long qoff = ((long)b * 2048 + q0 + l16) * 3072 + h * 64;
  const bf16x8 bq0 = *(const bf16x8*)&qkv[qoff + quad * 8];
  const bf16x8 bq1 = *(const bf16x8*)&qkv[qoff + 32 + quad * 8];

  const int srow = lane >> 3;
  const int cslot = lane & 7;
  const int cg = cslot ^ srow;

  floatx4 o[4];
#pragma unroll
  for (int mi = 0; mi < 4; mi++) o[mi] = (floatx4){0.f, 0.f, 0.f, 0.f};
  float mrow = -3.0e38f, lrow = 0.f;

  for (int t = 0; t < 32; ++t) {
    __syncthreads();
#pragma unroll
    for (int j = 0; j < 2; ++j) {
      const int rloc = wave * 16 + j * 8 + srow;
      gll16(kb + (long)(t * 64 + rloc) * 3072 + cg * 8,
            &lK[(wave * 16 + j * 8) * 64]);
      gll16(vb + (long)rloc * 2048 + t * 64 + cg * 8,
            &lV[(wave * 16 + j * 8) * 64]);
    }
    __syncthreads();

    floatx4 c[4];
#pragma unroll
    for (int g = 0; g < 4; ++g) {
      const bf16x8 a0 =
          *(const bf16x8*)&lK[(g * 16 + l16) * 64 + ((quad) ^ (l16 & 7)) * 8];
      const bf16x8 a1 =
          *(const bf16x8*)&lK[(g * 16 + l16) * 64 + ((4 + quad) ^ (l16 & 7)) * 8];
      floatx4 cc = {0.f, 0.f, 0.f, 0.f};
      cc = MFMA16(a0, bq0, cc);
      cc = MFMA16(a1, bq1, cc);
      c[g] = cc;
    }
    float s[4][4];
    float tm = -3.0e38f;
#pragma unroll
    for (int g = 0; g < 4; ++g) {
      const float4 a4 = *(const float4*)&am[t * 64 + g * 16 + quad * 4];
#pragma unroll
      for (int r = 0; r < 4; ++r) {
        const float av = r == 0 ? a4.x : (r == 1 ? a4.y : (r == 2 ? a4.z : a4.w));
        s[g][r] = c[g][r] * cs + av;
        tm = fmaxf(tm, s[g][r]);
      }
    }
    tm = fmaxf(tm, __shfl_xor(tm, 16));
    tm = fmaxf(tm, __shfl_xor(tm, 32));
    const float mnew = fmaxf(mrow, tm);
    const float alpha = exp2f(mrow - mnew);
    mrow = mnew;
    float p[4][4], rs = 0.f;
#pragma unroll
    for (int g = 0; g < 4; ++g)
#pragma unroll
      for (int r = 0; r < 4; ++r) {
        p[g][r] = exp2f(s[g][r] - mnew);
        rs += p[g][r];
      }
    rs += __shfl_xor(rs, 16);
    rs += __shfl_xor(rs, 32);
    lrow = lrow * alpha + rs;
#pragma unroll
    for (int mi = 0; mi < 4; mi++) o[mi] *= alpha;

    unsigned dw[4][2];
#pragma unroll
    for (int g = 0; g < 4; ++g) {
      dw[g][0] = pk(p[g][0], p[g][1]);
      dw[g][1] = pk(p[g][2], p[g][3]);
    }
    const int qs0 = (quad & 1) * 2;
    const int src0 = l16 + 16 * qs0, src1 = src0 + 16;
    const bool hig = (quad >> 1) != 0;
#pragma unroll
    for (int ss = 0; ss < 2; ++ss) {
      const unsigned a0 = __shfl((int)dw[2 * ss][0], src0);
      const unsigned b0 = __shfl((int)dw[2 * ss + 1][0], src0);
      const unsigned a1 = __shfl((int)dw[2 * ss][1], src0);
      const unsigned b1 = __shfl((int)dw[2 * ss + 1][1], src0);
      const unsigned a2 = __shfl((int)dw[2 * ss][0], src1);
      const unsigned b2 = __shfl((int)dw[2 * ss + 1][0], src1);
      const unsigned a3 = __shfl((int)dw[2 * ss][1], src1);
      const unsigned b3 = __shfl((int)dw[2 * ss + 1][1], src1);
      uint4 du;
      du.x = hig ? b0 : a0;
      du.y = hig ? b1 : a1;
      du.z = hig ? b2 : a2;
      du.w = hig ? b3 : a3;
      const bf16x8 bp = *reinterpret_cast<bf16x8*>(&du);
#pragma unroll
      for (int mi = 0; mi < 4; ++mi) {
        const bf16x8 av = *(const bf16x8*)&lV[(mi * 16 + l16) * 64 +
                                              ((ss * 4 + quad) ^ (l16 & 7)) * 8];
        o[mi] = MFMA16(av, bp, o[mi]);
      }
    }
  }

  const float inv_l = 1.f / lrow;
  const long cb = ((long)b * 2048 + q0 + l16) * 1024 + h * 64;
#pragma unroll
  for (int mi = 0; mi < 4; mi++) {
    short4v w;
#pragma unroll
    for (int r = 0; r < 4; r++) w[r] = bf16bits(o[mi][r] * inv_l);
    *(short4v*)&ctx[cb + mi * 16 + quad * 4] = w;
  }
}

// ---------------------------------------------------------------------------
// ws plan (peak 32 MiB) + d_out (16 MiB) as scratch — identical to round 9:
//  A: wqkvT ws[24,30) (one merged launch); ln1 x->xn(d_out[0,8) bf16);
//     qkv-gemm -> qkv ws[0,24)
//  B: vtrans -> vtb ws[24,32); mask2add -> addm(d_out+12M, 16KB);
//     attn(qkv,vtb,addm) -> ctxb(d_out[0,8) bf16)
//  C: woT -> d_out[8,10); wo-gemm64(ctxb,woT)+x -> x1 f32 ws[0,16)  (EPI1)
//  D: ln2 x1 -> xn2(d_out[0,8) bf16)
//  E c=0..1 (half=2048): w1Th -> d_out[8,12); ffn1(xn2,w1Th,+b1,relu)
//       -> hc ws[16,32) bf16; w2Th -> d_out[12,16);
//       ffn2-gemm64: x1 += hc@w2Th^T (EPI3, K=2048)
//  F: bias_add: d_out = x1 + b2 (fp32)
// ---------------------------------------------------------------------------
extern "C" void kernel_launch(void* const* d_in, const int* in_sizes, int n_in,
                              void* d_out, int out_size, void* d_ws, size_t ws_size,
                              hipStream_t stream) {
  const float* x = (const float*)d_in[0];
  const int* mask = (const int*)d_in[1];
  const float* wq = (const float*)d_in[2];
  const float* wk = (const float*)d_in[3];
  const float* wv = (const float*)d_in[4];
  const float* wo = (const float*)d_in[5];
  const float* w1 = (const float*)d_in[6];
  const float* b1 = (const float*)d_in[7];
  const float* w2 = (const float*)d_in[8];
  const float* b2 = (const float*)d_in[9];
  const float* alpha1 = (const float*)d_in[10];
  const float* bias1 = (const float*)d_in[11];
  const float* alpha2 = (const float*)d_in[12];
  const float* bias2 = (const float*)d_in[13];

  char* ws = (char*)d_ws;
  char* dob = (char*)d_out;
  const size_t MiB = 1048576;
  __hip_bfloat16* qkv   = (__hip_bfloat16*)(ws + 0);          // [0,24)
  __hip_bfloat16* wqkvT = (__hip_bfloat16*)(ws + 24 * MiB);   // [24,30)
  __hip_bfloat16* vtb   = (__hip_bfloat16*)(ws + 24 * MiB);   // [24,32)
  float*          x1    = (float*)(ws + 0);                   // [0,16) f32
  __hip_bfloat16* hc    = (__hip_bfloat16*)(ws + 16 * MiB);   // [16,32)
  __hip_bfloat16* xn    = (__hip_bfloat16*)d_out;             // d_out[0,8) bf16
  __hip_bfloat16* ctxb  = (__hip_bfloat16*)d_out;
  __hip_bfloat16* xn2   = (__hip_bfloat16*)d_out;
  __hip_bfloat16* woT   = (__hip_bfloat16*)(dob + 8 * MiB);   // d_out[8,10)
  __hip_bfloat16* w1Th  = (__hip_bfloat16*)(dob + 8 * MiB);   // d_out[8,12)
  __hip_bfloat16* w2Th  = (__hip_bfloat16*)(dob + 12 * MiB);  // d_out[12,16)
  float*          addm  = (float*)(dob + 12 * MiB);           // d_out[12M,+16K)

  const dim3 b256(256);
  const dim3 g1k(16, 16);
  // Stage A
  transpose_qkv_kernel<<<dim3(16, 48), b256, 0, stream>>>(wq, wk, wv, wqkvT);
  ln_kernel<<<4096, b256, 0, stream>>>(x, xn, alpha1, bias1);
  gemm_bt_kernel<0><<<dim3(24, 32), b256, 0, stream>>>(xn, wqkvT, qkv, nullptr, nullptr,
                                                       4096, 3072, 1024);
  // Stage B
  vtrans_kernel<<<dim3(32, 32), b256, 0, stream>>>(qkv, vtb);
  mask2add_kernel<<<16, b256, 0, stream>>>(mask, addm);
  attn_kernel<<<dim3(32, 32), b256, 0, stream>>>(qkv, vtb, addm, ctxb);
  // Stage C
  transpose_f2b_kernel<<<g1k, b256, 0, stream>>>(wo, woT, 1024, 1024, 1024);
  gemm64_bt_kernel<1><<<dim3(16, 32), b256, 0, stream>>>(ctxb, woT, x1, nullptr, x,
                                                         4096, 1024, 1024);
  // Stage D
  ln_kernel<<<4096, b256, 0, stream>>>(x1, xn2, alpha2, bias2);
  // Stage E: FFN in 2 hidden-halves of 2048
  for (int c = 0; c < 2; ++c) {
    transpose_f2b_kernel<<<dim3(32, 16), b256, 0, stream>>>(w1 + c * 2048, w1Th,
                                                            1024, 2048, 4096);
    gemm_bt_kernel<2><<<dim3(16, 32), b256, 0, stream>>>(xn2, w1Th, hc, b1 + c * 2048,
                                                         nullptr, 4096, 2048, 1024);
    transpose_f2b_kernel<<<dim3(16, 32), b256, 0, stream>>>(w2 + (size_t)c * 2048 * 1024,
                                                            w2Th, 2048, 1024, 1024);
    gemm64_bt_kernel<3><<<dim3(16, 32), b256, 0, stream>>>(hc, w2Th, x1, nullptr,
                                                           nullptr, 4096, 1024, 2048);
  }
  // Stage F
  bias_add_kernel<<<4096, b256, 0, stream>>>(x1, b2, (float*)d_out);
}